// Round 10
// baseline (422.616 us; speedup 1.0000x reference)
//
#include <hip/hip_runtime.h>
#include <hip/hip_bf16.h>

#define NN 3600
#define MP 3712          // 29*128 (row-major feat padding)
#define KADJ 3616        // 113*32 padded node-count for adjacency K
#define NH (3600*512)
#define EE 230400
#define NKT0 9           // L0 K = 1152 = 9*128 (588+512 padded)
#define NKT1 12          // L1 K = 1536 = 12*128 (1024 x1 + 512 h0)

typedef __hip_bfloat16 bf16;
typedef __bf16 bf16x8 __attribute__((ext_vector_type(8)));
typedef float f32x4 __attribute__((ext_vector_type(4)));
typedef int i32x8 __attribute__((ext_vector_type(8)));
typedef unsigned char u8x16 __attribute__((ext_vector_type(16)));

typedef __attribute__((address_space(1))) void as1v;
typedef __attribute__((address_space(3))) void as3v;

__device__ __forceinline__ void glds16(void* lds, const void* g) {
  __builtin_amdgcn_global_load_lds((as1v*)(void*)g, (as3v*)lds, 16, 0, 0);
}

__device__ __forceinline__ float sigm(float v) { return 1.0f / (1.0f + expf(-v)); }

__device__ __forceinline__ unsigned char f2fp8(float f) {
  return (unsigned char)(__builtin_amdgcn_cvt_pk_fp8_f32(f, 0.f, 0, false) & 0xff);
}

// ------------- MX-fp8 fused LSTM GEMM, 256x256 tile, 8 waves ---------------
// Operands tiled: [blk128][kt][kb:4][row:128][32B] fp8 e4m3, K-step = 128.
// A covers blk 2*by, 2*by+1 ; B covers blk 2*nblk, 2*nblk+1.
// Wave (wr=w>>1, wc=w&1): A rows wr*64..+64, B cols wc*128..+128.
// B gate-interleaved: packed col R <-> gate R&... gate = nf&3,
// hidden j = (nblk*4 + wc*2 + (nf>>2))*16 + (l&15).
// MODE 0: write h (fp8) into tiled A1X (8-kt stride) at k = dirOff+jh.
// MODE 1: write h*0.01 (bf16) into Afeat row-major at col colOff+jh.
// Grid ALWAYS (16,15) = 240 blocks; XCD chunk swizzle (240 = 8*30).
template<int MODE>
__global__ __launch_bounds__(512, 2) void gemm_lstm8(
    const unsigned char* __restrict__ Axf, const unsigned char* __restrict__ Ahf,
    const unsigned char* __restrict__ Bf,
    const float* __restrict__ c0f, const float* __restrict__ bihf,
    const float* __restrict__ bhhf,
    const unsigned char* __restrict__ Axb, const unsigned char* __restrict__ Ahb,
    const unsigned char* __restrict__ Bb,
    const float* __restrict__ c0b, const float* __restrict__ bihb,
    const float* __restrict__ bhhb,
    void* __restrict__ dst1,
    int nktx, int nkt, int hx)
{
  __shared__ alignas(16) unsigned char smem[131072];  // 2 x (A0|A1|B0|B1) x16KB
  const int hid = (int)blockIdx.y * 16 + (int)blockIdx.x;
  const int swz = (hid & 7) * 30 + (hid >> 3);        // bijective, 240=8*30
  const int bx = swz & 15, by = swz >> 4;             // bx 0..15, by 0..14
  const bool back = bx >= hx;                          // hx = 8
  const unsigned char* Ax = back ? Axb : Axf;
  const unsigned char* Ah = back ? Ahb : Ahf;
  const unsigned char* B  = back ? Bb  : Bf;
  const float* c0  = back ? c0b : c0f;
  const float* bih = back ? bihb : bihf;
  const float* bhh = back ? bhhb : bhhf;
  const int t = threadIdx.x, w = t >> 6, l = t & 63;
  const int wr = w >> 1, wc = w & 1;
  const int nblk = back ? bx - hx : bx;               // 0..7
  const int nkth = nkt - nktx;
  const unsigned char* gAx0 = Ax + (((size_t)(2*by)   * nktx) << 14);
  const unsigned char* gAx1 = Ax + (((size_t)(2*by+1) * nktx) << 14);
  const unsigned char* gAh0 = Ah + (((size_t)(2*by)   * nkth) << 14);
  const unsigned char* gAh1 = Ah + (((size_t)(2*by+1) * nkth) << 14);
  const unsigned char* gB0  = B  + (((size_t)(2*nblk)   * nkt) << 14);
  const unsigned char* gB1  = B  + (((size_t)(2*nblk+1) * nkt) << 14);
  const int kb = l >> 4;
  // A frag: row-in-256 = wr*64 + mi*16 + (l&15); quadrant = wr>>1
  const int aoff = (wr >> 1) * 16384 + kb*4096 + ((wr & 1)*64 + (l & 15))*32;
  // B frag: col-in-256 = wc*128 + nf*16 + (l&15)
  const int boff = 32768 + wc*16384 + kb*4096 + (l & 15)*32;
  f32x4 acc[4][8] = {};

  auto STAGE = [&](int buf, int kt) {
    unsigned char* ld = smem + buf*65536;
    const unsigned char *sA0, *sA1;
    if (kt < nktx) { sA0 = gAx0 + ((size_t)kt << 14); sA1 = gAx1 + ((size_t)kt << 14); }
    else { sA0 = gAh0 + ((size_t)(kt - nktx) << 14); sA1 = gAh1 + ((size_t)(kt - nktx) << 14); }
    const unsigned char* sB0 = gB0 + ((size_t)kt << 14);
    const unsigned char* sB1 = gB1 + ((size_t)kt << 14);
    glds16(ld + t*16,          sA0 + t*16);
    glds16(ld + 8192 + t*16,   sA0 + 8192 + t*16);
    glds16(ld + 16384 + t*16,  sA1 + t*16);
    glds16(ld + 24576 + t*16,  sA1 + 8192 + t*16);
    glds16(ld + 32768 + t*16,  sB0 + t*16);
    glds16(ld + 40960 + t*16,  sB0 + 8192 + t*16);
    glds16(ld + 49152 + t*16,  sB1 + t*16);
    glds16(ld + 57344 + t*16,  sB1 + 8192 + t*16);
  };

  STAGE(0, 0);
  STAGE(1, 1);                 // 16 loads in flight
  int cur = 0;
  for (int kt = 0; kt < nkt; ++kt) {
    if (kt + 1 < nkt) asm volatile("s_waitcnt vmcnt(8)" ::: "memory");
    else              asm volatile("s_waitcnt vmcnt(0)" ::: "memory");
    __builtin_amdgcn_sched_barrier(0);
    __builtin_amdgcn_s_barrier();
    __builtin_amdgcn_sched_barrier(0);
    const unsigned char* base = smem + cur*65536;
    i32x8 a4[4];
#pragma unroll
    for (int mi = 0; mi < 4; ++mi) a4[mi] = *(const i32x8*)(base + aoff + mi*512);
#pragma unroll
    for (int nf = 0; nf < 8; ++nf) {
      const i32x8 bfr = *(const i32x8*)(base + boff + nf*512);
#pragma unroll
      for (int mi = 0; mi < 4; ++mi)
        acc[mi][nf] = __builtin_amdgcn_mfma_scale_f32_16x16x128_f8f6f4(
            a4[mi], bfr, acc[mi][nf], 0, 0, 0, 127, 0, 127);
    }
    __builtin_amdgcn_sched_barrier(0);
    __builtin_amdgcn_s_barrier();      // all waves done reading buf[cur]
    __builtin_amdgcn_sched_barrier(0);
    if (kt + 2 < nkt) STAGE(cur, kt + 2);
    cur ^= 1;
  }
  // C/D layout: col = lane&15, row = (lane>>4)*4 + reg  [m89/m121-128]
  const int crow = by*256 + wr*64 + ((l >> 4) << 2);
  const int jbase = (nblk*4 + wc*2) * 16 + (l & 15);
#pragma unroll
  for (int ng = 0; ng < 2; ++ng) {
    const int jh = jbase + ng*16;
    const float bI = bih[jh]        + bhh[jh];
    const float bF = bih[512 + jh]  + bhh[512 + jh];
    const float bG = bih[1024 + jh] + bhh[1024 + jh];
    const float bO = bih[1536 + jh] + bhh[1536 + jh];
    const int kk = (back ? 512 : 0) + jh;
    const size_t kpart = ((size_t)(kk >> 7) << 14) + ((size_t)((kk >> 5) & 3) << 12) + (kk & 31);
    const int colOff = back ? 896 : 384;
#pragma unroll
    for (int mi = 0; mi < 4; ++mi)
#pragma unroll
      for (int jr = 0; jr < 4; ++jr) {
        const int n = crow + mi*16 + jr;
        if (n < NN) {
          const float gi = acc[mi][ng*4 + 0][jr] + bI;
          const float gf = acc[mi][ng*4 + 1][jr] + bF;
          const float gg = acc[mi][ng*4 + 2][jr] + bG;
          const float go = acc[mi][ng*4 + 3][jr] + bO;
          const float c2 = sigm(gf) * c0[(size_t)n*512 + jh] + sigm(gi) * tanhf(gg);
          const float h  = sigm(go) * tanhf(c2);
          if (MODE == 0) {
            const size_t off = (((size_t)(n >> 7) * 8) << 14) + kpart + ((size_t)(n & 127) << 5);
            ((unsigned char*)dst1)[off] = f2fp8(h);
          } else {
            ((bf16*)dst1)[(size_t)n*1408 + colOff + jh] = __float2bfloat16(h * 0.01f);
          }
        }
      }
  }
}

// ---------------- split-K GEMM (bf16), counted-vmcnt pipeline (r8) ----------
__global__ __launch_bounds__(256) void gemm_bt_sk(const bf16* __restrict__ A,
                                                  const bf16* __restrict__ B,
                                                  float* __restrict__ Cp,
                                                  int Kp, int ldc, int ksteps)
{
  __shared__ alignas(16) char smem[32768];   // 2 x (A 8KB | B 8KB)
  const int t = threadIdx.x, w = t >> 6, l = t & 63;
  const int mbase = blockIdx.y << 7, nbase = blockIdx.x << 7;
  const int total = Kp >> 5;
  const int kstart = blockIdx.z * ksteps;
  int steps = total - kstart; if (steps > ksteps) steps = ksteps;
  const size_t ldb = (size_t)Kp * 2;
  const char* gA = (const char*)A + (size_t)(mbase + w*16 + (l>>2)) * ldb
                   + (size_t)((l&3)*16) + (size_t)kstart*64;
  const char* gB = (const char*)B + (size_t)(nbase + w*16 + (l>>2)) * ldb
                   + (size_t)((l&3)*16) + (size_t)kstart*64;
  const int wm = (w>>1)*64, wn = (w&1)*64;
  const int aoff = (wm + (l&15))*64 + (l>>4)*16;
  const int boff = 8192 + (wn + (l&15))*64 + (l>>4)*16;
  f32x4 acc[4][4] = {};
  const size_t chunk = ldb * 64;

  auto STAGE = [&](int buf, int kt) {
    char* lA = smem + buf*16384 + w*1024;
    char* lB = smem + buf*16384 + 8192 + w*1024;
    const size_t ko = (size_t)kt * 64;
    glds16(lA,        gA + ko);
    glds16(lA + 4096, gA + ko + chunk);
    glds16(lB,        gB + ko);
    glds16(lB + 4096, gB + ko + chunk);
  };

  STAGE(0, 0);
  if (steps > 1) STAGE(1, 1);
  int cur = 0;
  for (int kt = 0; kt < steps; ++kt) {
    if (kt + 1 < steps) asm volatile("s_waitcnt vmcnt(4)" ::: "memory");
    else                asm volatile("s_waitcnt vmcnt(0)" ::: "memory");
    __builtin_amdgcn_sched_barrier(0);
    __builtin_amdgcn_s_barrier();
    __builtin_amdgcn_sched_barrier(0);
    const char* base = smem + cur*16384;
    bf16x8 av[4], bv[4];
#pragma unroll
    for (int mi = 0; mi < 4; ++mi) av[mi] = *(const bf16x8*)(base + aoff + mi*1024);
#pragma unroll
    for (int ni = 0; ni < 4; ++ni) bv[ni] = *(const bf16x8*)(base + boff + ni*1024);
#pragma unroll
    for (int mi = 0; mi < 4; ++mi)
#pragma unroll
      for (int ni = 0; ni < 4; ++ni)
        acc[mi][ni] = __builtin_amdgcn_mfma_f32_16x16x32_bf16(av[mi], bv[ni], acc[mi][ni], 0, 0, 0);
    __builtin_amdgcn_sched_barrier(0);
    __builtin_amdgcn_s_barrier();
    __builtin_amdgcn_sched_barrier(0);
    if (kt + 2 < steps) STAGE(cur, kt + 2);
    cur ^= 1;
  }
  float* Cz = Cp + (size_t)blockIdx.z * ((size_t)(gridDim.y << 7) * ldc);
  const int crow = mbase + wm + ((l>>4)<<2);
  const int ccol = nbase + wn + (l&15);
#pragma unroll
  for (int mi = 0; mi < 4; ++mi)
#pragma unroll
    for (int ni = 0; ni < 4; ++ni) {
      float* cp = Cz + (size_t)(crow + mi*16)*ldc + (ccol + ni*16);
#pragma unroll
      for (int j = 0; j < 4; ++j) cp[(size_t)j*ldc] = acc[mi][ni][j];
    }
}

// ---------------- reduce kernels ----------------
__global__ void reduce_bf_pad(const float* __restrict__ p, bf16* __restrict__ dst, int Z)
{
  int k = blockIdx.x*256 + threadIdx.x;
  int r = blockIdx.y;
  if (k >= KADJ) return;
  const size_t psz = (size_t)gridDim.y * MP;
  float s = 0.f;
  if (k < NN)
    for (int z = 0; z < Z; ++z) s += p[(size_t)z*psz + (size_t)r*MP + k];
  dst[(size_t)r*KADJ + k] = __float2bfloat16(s);
}

__global__ void reduce_relu_bf(const float* __restrict__ p, const float* __restrict__ b,
                               bf16* __restrict__ dst)
{
  int idx = blockIdx.x*256 + threadIdx.x;   // MP*512
  int f = idx & 511;
  float s = b[f];
#pragma unroll
  for (int z = 0; z < 4; ++z) s += p[(size_t)z*MP*512 + idx];
  dst[idx] = __float2bfloat16(fmaxf(s, 0.f));
}

__global__ void reduce_bias_out(const float* __restrict__ p, const float* __restrict__ b,
                                float* __restrict__ out)
{
  int idx = blockIdx.x*256 + threadIdx.x;   // NN*256
  if (idx >= NN*256) return;
  int f = idx & 255;
  float s = b[f];
#pragma unroll
  for (int z = 0; z < 8; ++z) s += p[(size_t)z*MP*256 + idx];
  out[idx] = s;
}

// ---------------- fp8 tiled packing ----------------
// dst layout: [blk128][kt][kb:4][r:128][32B]; thread t covers row t>>1, 16 bytes
__global__ void pack_B_8(const float* __restrict__ wih, const float* __restrict__ whh,
                         unsigned char* __restrict__ dst, int kx, int nkt)
{
  const int kt = blockIdx.x >> 2, kbId = blockIdx.x & 3;
  const int t = threadIdx.x;
  const int r = t >> 1, kio = (t & 1) << 4;
  const int R = ((int)blockIdx.y << 7) + r;
  const int src = (((R >> 4) & 3) << 9) + ((R >> 6) << 4) + (R & 15);
  const int kbase = kt*128 + kbId*32 + kio;
  u8x16 v;
#pragma unroll
  for (int i = 0; i < 16; ++i) {
    const int k = kbase + i;
    float f = 0.f;
    if (k < kx) f = wih[(size_t)src*kx + k];
    else if (k < kx + 512) f = whh[(size_t)src*512 + (k - kx)];
    v[i] = f2fp8(f);
  }
  *(u8x16*)(dst + (((size_t)blockIdx.y*nkt + kt) << 14) + (kbId << 12) + (r << 5) + kio) = v;
}

__global__ void pack_A0_8(const float* __restrict__ x, const float* __restrict__ h0,
                          unsigned char* __restrict__ a0f, unsigned char* __restrict__ a0b)
{
  const int kt = blockIdx.x >> 2, kbId = blockIdx.x & 3;
  const int t = threadIdx.x;
  const int r = t >> 1, kio = (t & 1) << 4;
  const int n = ((int)blockIdx.y << 7) + r;
  const int kbase = kt*128 + kbId*32 + kio;
  const float* hsrc = h0 + (size_t)blockIdx.z * NH;
  u8x16 v;
#pragma unroll
  for (int i = 0; i < 16; ++i) {
    const int k = kbase + i;
    float f = 0.f;
    if (n < NN) {
      if (k < 588) f = x[(size_t)n*972 + k];
      else if (k < 1100) f = hsrc[(size_t)n*512 + (k - 588)];
    }
    v[i] = f2fp8(f);
  }
  unsigned char* dst = blockIdx.z ? a0b : a0f;
  *(u8x16*)(dst + (((size_t)blockIdx.y*NKT0 + kt) << 14) + (kbId << 12) + (r << 5) + kio) = v;
}

// h0-tail of L1 A: 4 kt per direction, local kt 0..3 (k in [1024,1536))
__global__ void pack_A1h_8(const float* __restrict__ h0,
                           unsigned char* __restrict__ ahf, unsigned char* __restrict__ ahb)
{
  const int ktl = blockIdx.x >> 2, kbId = blockIdx.x & 3;   // ktl 0..3
  const int t = threadIdx.x;
  const int r = t >> 1, kio = (t & 1) << 4;
  const int n = ((int)blockIdx.y << 7) + r;
  const int kbase = ktl*128 + kbId*32 + kio;                // k-1024
  const float* hsrc = h0 + (size_t)(2 + blockIdx.z) * NH;
  u8x16 v;
#pragma unroll
  for (int i = 0; i < 16; ++i) {
    const int k = kbase + i;
    float f = (n < NN) ? hsrc[(size_t)n*512 + k] : 0.f;
    v[i] = f2fp8(f);
  }
  unsigned char* dst = blockIdx.z ? ahb : ahf;
  *(u8x16*)(dst + (((size_t)blockIdx.y*4 + ktl) << 14) + (kbId << 12) + (r << 5) + kio) = v;
}

// ---------------- bf16 packing (GCN path) ----------------
__global__ void pack_BT(const float* __restrict__ W, bf16* __restrict__ dst, int Nc, int K)
{
  int k = blockIdx.x*256 + threadIdx.x;
  int n = blockIdx.y;
  if (k >= K) return;
  dst[(size_t)n*K + k] = __float2bfloat16(W[(size_t)k*Nc + n]);
}

__global__ void pack_prot(const float* __restrict__ x, bf16* __restrict__ afeat)
{
  int k = blockIdx.x*256 + threadIdx.x;    // [0,384)
  int n = blockIdx.y;
  if (k >= 384) return;
  float v = (n < NN) ? x[(size_t)n*972 + 588 + k] : 0.f;
  afeat[(size_t)n*1408 + k] = __float2bfloat16(v);
}

// ---------------- degree / norm ----------------
__global__ void deg_count(const int* __restrict__ ecols, int* __restrict__ deg)
{
  int e = blockIdx.x*256 + threadIdx.x;
  if (e < EE) atomicAdd(&deg[ecols[e]], 1);
}

__global__ void calc_dinv(const int* __restrict__ deg, float* __restrict__ dinv)
{
  int n = blockIdx.x*256 + threadIdx.x;
  if (n < NN) dinv[n] = 1.0f / sqrtf((float)(deg[n] + 1));
}

// ---------------- dense normalized adjacency build ----------------
__global__ void adj_scatter(const int* __restrict__ er, const int* __restrict__ ec,
                            const float* __restrict__ dinv, float* __restrict__ adjf)
{
  int e = blockIdx.x*256 + threadIdx.x;
  if (e < EE) {
    int r = er[e], c = ec[e];
    atomicAdd(&adjf[(size_t)c*KADJ + r], dinv[r]*dinv[c]);
  } else if (e < EE + NN) {
    int n = e - EE;
    float d = dinv[n];
    atomicAdd(&adjf[(size_t)n*KADJ + n], d*d);
  }
}

__global__ void cvt_bf(const float* __restrict__ src, int lds,
                       bf16* __restrict__ dst, int rv, int kv)
{
  int k = blockIdx.x*256 + threadIdx.x;
  int r = blockIdx.y;
  if (k >= KADJ) return;
  float v = (r < rv && k < kv) ? src[(size_t)r*lds + k] : 0.f;
  dst[(size_t)r*KADJ + k] = __float2bfloat16(v);
}

// ---------------- workspace layout (bytes), total <= 93,339,648 (proven) ----
#define OFF_DEG   ((size_t)0)
#define OFF_DINV  ((size_t)16384)
#define OFF_BW2   ((size_t)32768)
#define OFF_B0F   ((size_t)294912)     // fp8: 2,359,296
#define OFF_B0B   ((size_t)4882432)
#define OFF_B1F   ((size_t)9469952)    // fp8: 3,145,728
#define OFF_B1B   ((size_t)15761408)
#define OFF_BW1   ((size_t)22052864)
#define OFF_A0F   ((size_t)23494656)   // fp8 30-blk: 4,423,680
#define OFF_A0B   ((size_t)31809536)   // -> 36,233,216
#define OFF_A1X   ((size_t)40124416)   // shared x1, 30 blk x 8kt: 3,932,160
#define OFF_A1HF  ((size_t)44056576)   // h0 tail fwd, 30 blk x 4kt: 1,966,080
#define OFF_A1HB  ((size_t)46022656)   // -> 47,988,736
#define OFF_G     ((size_t)62930944)
// ---- overlays (temporal reuse) ----
#define OFF_AFEAT OFF_A0F              // alive: pack_prot .. xwt1 gemm
#define OFF_XW1P  OFF_G                // xwt1 partials 30,408,704
#define OFF_XWT1B OFF_B0F              // 3,702,784 (B0 dead after L0)
#define OFF_ADJF  ((size_t)40124416)   // 52,070,400 (A1+xw1p dead after xwt1+reduce)
#define OFF_ADJB  ((size_t)4194304)    // 26,845,184 (B0b/B1/BW1/Afeat dead)
#define OFF_H1P   ((size_t)40124416)   // agg1 partials (adjf dead)
#define OFF_H1    ((size_t)70533120)
#define OFF_XW2P  ((size_t)74334208)
#define OFF_XWT2B ((size_t)89538560)
#define OFF_O2P   ((size_t)40124416)   // agg2 partials (h1p dead)

extern "C" void kernel_launch(void* const* d_in, const int* in_sizes, int n_in,
                              void* d_out, int out_size, void* d_ws, size_t ws_size,
                              hipStream_t stream)
{
  const float* x    = (const float*)d_in[0];
  const int*   ei   = (const int*)d_in[1];
  const float* h0   = (const float*)d_in[2];
  const float* c0   = (const float*)d_in[3];
  const float* wih0f = (const float*)d_in[4];
  const float* whh0f = (const float*)d_in[5];
  const float* bih0f = (const float*)d_in[6];
  const float* bhh0f = (const float*)d_in[7];
  const float* wih0b = (const float*)d_in[8];
  const float* whh0b = (const float*)d_in[9];
  const float* bih0b = (const float*)d_in[10];
  const float* bhh0b = (const float*)d_in[11];
  const float* wih1f = (const float*)d_in[12];
  const float* whh1f = (const float*)d_in[13];
  const float* bih1f = (const float*)d_in[14];
  const float* bhh1f = (const float*)d_in[15];
  const float* wih1b = (const float*)d_in[16];
  const float* whh1b = (const float*)d_in[17];
  const float* bih1b = (const float*)d_in[18];
  const float* bhh1b = (const float*)d_in[19];
  const float* W1 = (const float*)d_in[20];
  const float* b1 = (const float*)d_in[21];
  const float* W2 = (const float*)d_in[22];
  const float* b2 = (const float*)d_in[23];

  char* ws = (char*)d_ws;
  int*   deg  = (int*)(ws + OFF_DEG);
  float* dinv = (float*)(ws + OFF_DINV);
  unsigned char* B0f8 = (unsigned char*)(ws + OFF_B0F);
  unsigned char* B0b8 = (unsigned char*)(ws + OFF_B0B);
  unsigned char* B1f8 = (unsigned char*)(ws + OFF_B1F);
  unsigned char* B1b8 = (unsigned char*)(ws + OFF_B1B);
  bf16* BW1 = (bf16*)(ws + OFF_BW1);
  bf16* BW2 = (bf16*)(ws + OFF_BW2);
  unsigned char* A0f8 = (unsigned char*)(ws + OFF_A0F);
  unsigned char* A0b8 = (unsigned char*)(ws + OFF_A0B);
  unsigned char* A1X8 = (unsigned char*)(ws + OFF_A1X);
  unsigned char* A1HF = (unsigned char*)(ws + OFF_A1HF);
  unsigned char* A1HB = (unsigned char*)(ws + OFF_A1HB);
  bf16* Afeat = (bf16*)(ws + OFF_AFEAT);
  float* xw1p  = (float*)(ws + OFF_XW1P);
  bf16*  xwt1b = (bf16*)(ws + OFF_XWT1B);
  float* adjf  = (float*)(ws + OFF_ADJF);
  bf16*  adjb  = (bf16*)(ws + OFF_ADJB);
  float* h1p   = (float*)(ws + OFF_H1P);
  bf16*  h1bf  = (bf16*)(ws + OFF_H1);
  float* xw2p  = (float*)(ws + OFF_XW2P);
  bf16*  xwt2b = (bf16*)(ws + OFF_XWT2B);
  float* o2p   = (float*)(ws + OFF_O2P);
  float* outp = (float*)d_out;

  // degree + norm
  hipMemsetAsync(deg, 0, (size_t)NN*4, stream);
  deg_count<<<dim3((EE+255)/256), 256, 0, stream>>>(ei + EE, deg);
  calc_dinv<<<dim3(15), 256, 0, stream>>>(deg, dinv);

  // weight packing: fp8 tiled (LSTM), bf16 (GCN)
  pack_B_8<<<dim3(NKT0*4, 16), 256, 0, stream>>>(wih0f, whh0f, B0f8, 588, NKT0);
  pack_B_8<<<dim3(NKT0*4, 16), 256, 0, stream>>>(wih0b, whh0b, B0b8, 588, NKT0);
  pack_B_8<<<dim3(NKT1*4, 16), 256, 0, stream>>>(wih1f, whh1f, B1f8, 1024, NKT1);
  pack_B_8<<<dim3(NKT1*4, 16), 256, 0, stream>>>(wih1b, whh1b, B1b8, 1024, NKT1);
  pack_BT<<<dim3(6, 512), 256, 0, stream>>>(W1, BW1, 512, 1408);
  pack_BT<<<dim3(2, 256), 256, 0, stream>>>(W2, BW2, 256, 512);

  // activations packing (fp8 tiled, 30 row-blocks for 256-tile M)
  pack_A0_8<<<dim3(NKT0*4, 30, 2), 256, 0, stream>>>(x, h0, A0f8, A0b8);
  pack_A1h_8<<<dim3(16, 30, 2), 256, 0, stream>>>(h0, A1HF, A1HB);

  // LSTM layer 0: 256x256 MX-fp8, merged f+b, gate fused; writes x1 into A1X
  gemm_lstm8<0><<<dim3(16, 15), 512, 0, stream>>>(
      A0f8, A0f8, B0f8, c0,              bih0f, bhh0f,
      A0b8, A0b8, B0b8, c0 + (size_t)NH, bih0b, bhh0b,
      A1X8, NKT0, NKT0, 8);

  // feat: prot part (A0 dead; Afeat overlays it)
  pack_prot<<<dim3(2, MP), 256, 0, stream>>>(x, Afeat);

  // LSTM layer 1: 256x256 MX-fp8, shared-x1 + per-dir h0 tail; writes into feat
  gemm_lstm8<1><<<dim3(16, 15), 512, 0, stream>>>(
      A1X8, A1HF, B1f8, c0 + (size_t)2*NH, bih1f, bhh1f,
      A1X8, A1HB, B1b8, c0 + (size_t)3*NH, bih1b, bhh1b,
      Afeat, 8, NKT1, 8);

  // XW1^T = W1^T @ feat^T  split-K=4 (bf16)
  gemm_bt_sk<<<dim3(29, 4, 4), 256, 0, stream>>>(BW1, Afeat, xw1p, 1408, MP, 11);
  reduce_bf_pad<<<dim3(15, 512), 256, 0, stream>>>(xw1p, xwt1b, 4);

  // dense normalized adjacency (A1+xw1p dead)
  hipMemsetAsync(adjf, 0, (size_t)NN*KADJ*4, stream);
  adj_scatter<<<dim3((EE+NN+255)/256), 256, 0, stream>>>(ei, ei + EE, dinv, adjf);
  cvt_bf<<<dim3(15, MP), 256, 0, stream>>>(adjf, KADJ, adjb, NN, KADJ);

  // out1 = relu(Adj @ XW1 + b1) -> bf16, split-K=4
  gemm_bt_sk<<<dim3(4, 29, 4), 256, 0, stream>>>(adjb, xwt1b, h1p, KADJ, 512, 29);
  reduce_relu_bf<<<dim3(MP*512/256), 256, 0, stream>>>(h1p, b1, h1bf);

  // XW2^T = W2^T @ h1^T  split-K=4
  gemm_bt_sk<<<dim3(29, 2, 4), 256, 0, stream>>>(BW2, h1bf, xw2p, 512, MP, 4);
  reduce_bf_pad<<<dim3(15, 256), 256, 0, stream>>>(xw2p, xwt2b, 4);

  // out = Adj @ XW2 + b2, split-K=8
  gemm_bt_sk<<<dim3(2, 29, 8), 256, 0, stream>>>(adjb, xwt2b, o2p, KADJ, 256, 15);
  reduce_bias_out<<<dim3(3600), 256, 0, stream>>>(o2p, b2, outp);
}

// Round 11
// 297.018 us; speedup vs baseline: 1.4229x; 1.4229x over previous
//
#include <hip/hip_runtime.h>
#include <hip/hip_bf16.h>

#define NN 3600
#define MP 3712          // 29*128 padded rows
#define KADJ 3616        // 113*32 padded node-count for adjacency K
#define NH (3600*512)
#define EE 230400
#define NKT0 9           // L0 K = 1152 = 9*128 (588+512 padded)
#define NKT1 12          // L1 K = 1536 = 12*128 (1024 x1 + 512 h0)

typedef __hip_bfloat16 bf16;
typedef __bf16 bf16x8 __attribute__((ext_vector_type(8)));
typedef float f32x4 __attribute__((ext_vector_type(4)));
typedef int i32x8 __attribute__((ext_vector_type(8)));
typedef unsigned char u8x16 __attribute__((ext_vector_type(16)));

typedef __attribute__((address_space(1))) void as1v;
typedef __attribute__((address_space(3))) void as3v;

__device__ __forceinline__ void glds16(void* lds, const void* g) {
  __builtin_amdgcn_global_load_lds((as1v*)(void*)g, (as3v*)lds, 16, 0, 0);
}

__device__ __forceinline__ float sigm(float v) { return 1.0f / (1.0f + expf(-v)); }

__device__ __forceinline__ unsigned char f2fp8(float f) {
  return (unsigned char)(__builtin_amdgcn_cvt_pk_fp8_f32(f, 0.f, 0, false) & 0xff);
}

__device__ __forceinline__ unsigned short f2bf_bits(float f) {
  __hip_bfloat16 h = __float2bfloat16(f);
  return *reinterpret_cast<unsigned short*>(&h);
}
__device__ __forceinline__ float bf_bits2f(unsigned short u) {
  __hip_bfloat16 h; *reinterpret_cast<unsigned short*>(&h) = u;
  return __bfloat162float(h);
}

// ---------------- MX-fp8 fused LSTM GEMM, counted-vmcnt + rect-XCD (r8) ----
// Operands tiled: [blk128][kt][kb:4][row:128][32B] fp8 e4m3, K-step = 128.
// A split: kt < nktx from Ax (per-dir or shared), kt >= nktx from Ah (per-dir).
// B gate-interleaved: packed col R <-> gate (R>>4)&3, hidden ((R>>6)<<4)+(R&15).
// MODE 0: write h (fp8) into tiled A1X (nkt=8 stride) at k = dirOff+jh.
// MODE 1: write h*0.01 (bf16) into Afeat row-major at col colOff+jh.
// Grid ALWAYS (32, 29): rect-XCD map (8 rects of 8bx x 14by + row 28).
template<int MODE>
__global__ __launch_bounds__(256) void gemm_lstm8(
    const unsigned char* __restrict__ Axf, const unsigned char* __restrict__ Ahf,
    const unsigned char* __restrict__ Bf,
    const float* __restrict__ c0f, const float* __restrict__ bihf,
    const float* __restrict__ bhhf,
    const unsigned char* __restrict__ Axb, const unsigned char* __restrict__ Ahb,
    const unsigned char* __restrict__ Bb,
    const float* __restrict__ c0b, const float* __restrict__ bihb,
    const float* __restrict__ bhhb,
    void* __restrict__ dst1,
    int nktx, int nkt, int hx)
{
  __shared__ alignas(16) unsigned char smem[65536];   // 2 x (A 16KB | B 16KB)
  const int hid = (int)blockIdx.y * 32 + (int)blockIdx.x;
  const int xcd = hid & 7, idx = hid >> 3;
  int bx, by;
  if (idx < 112) { bx = (xcd & 3) * 8 + (idx & 7); by = (xcd >> 2) * 14 + (idx >> 3); }
  else { int k = idx - 112; bx = (xcd & 3) * 8 + k * 2 + (xcd >> 2); by = 28; }
  const bool back = bx >= hx;
  const unsigned char* Ax = back ? Axb : Axf;
  const unsigned char* Ah = back ? Ahb : Ahf;
  const unsigned char* B  = back ? Bb  : Bf;
  const float* c0  = back ? c0b : c0f;
  const float* bih = back ? bihb : bihf;
  const float* bhh = back ? bhhb : bhhf;
  const int t = threadIdx.x, w = t >> 6, l = t & 63;
  const int nblk = back ? bx - hx : bx;
  const unsigned char* gA  = Ax + (((size_t)by * nktx) << 14) + t*16;
  const unsigned char* gAh = Ah + (((size_t)by * (nkt - nktx)) << 14) + t*16;
  const unsigned char* gB  = B  + (((size_t)nblk * nkt) << 14) + t*16;
  const int wm = (w>>1)*64, wn = (w&1)*64;
  const int kb = l >> 4;
  const int aoff = kb*4096 + (wm + (l&15))*32;
  const int boff = 16384 + kb*4096 + (wn + (l&15))*32;
  f32x4 acc[4][4] = {};

  auto STAGE = [&](int buf, int kt) {
    unsigned char* lA = smem + buf*32768 + w*1024;
    unsigned char* lB = smem + buf*32768 + 16384 + w*1024;
    const unsigned char* srcA = (kt < nktx) ? gA + ((size_t)kt << 14)
                                            : gAh + ((size_t)(kt - nktx) << 14);
    const size_t ko = (size_t)kt << 14;
    glds16(lA,          srcA);
    glds16(lA + 4096,   srcA + 4096);
    glds16(lA + 8192,   srcA + 8192);
    glds16(lA + 12288,  srcA + 12288);
    glds16(lB,          gB + ko);
    glds16(lB + 4096,   gB + ko + 4096);
    glds16(lB + 8192,   gB + ko + 8192);
    glds16(lB + 12288,  gB + ko + 12288);
  };

  STAGE(0, 0);
  STAGE(1, 1);                 // 16 loads in flight
  int cur = 0;
  for (int kt = 0; kt < nkt; ++kt) {
    if (kt + 1 < nkt) asm volatile("s_waitcnt vmcnt(8)" ::: "memory");
    else              asm volatile("s_waitcnt vmcnt(0)" ::: "memory");
    __builtin_amdgcn_sched_barrier(0);
    __builtin_amdgcn_s_barrier();
    __builtin_amdgcn_sched_barrier(0);
    const unsigned char* base = smem + cur*32768;
    i32x8 av[4], bv[4];
#pragma unroll
    for (int mi = 0; mi < 4; ++mi) av[mi] = *(const i32x8*)(base + aoff + mi*512);
#pragma unroll
    for (int ni = 0; ni < 4; ++ni) bv[ni] = *(const i32x8*)(base + boff + ni*512);
#pragma unroll
    for (int mi = 0; mi < 4; ++mi)
#pragma unroll
      for (int ni = 0; ni < 4; ++ni)
        acc[mi][ni] = __builtin_amdgcn_mfma_scale_f32_16x16x128_f8f6f4(
            av[mi], bv[ni], acc[mi][ni], 0, 0, 0, 127, 0, 127);
    __builtin_amdgcn_sched_barrier(0);
    __builtin_amdgcn_s_barrier();      // all waves done reading buf[cur]
    __builtin_amdgcn_sched_barrier(0);
    if (kt + 2 < nkt) STAGE(cur, kt + 2);
    cur ^= 1;
  }
  // C/D layout: col = lane&15, row = (lane>>4)*4 + reg  [m89/m121-128]
  const int jh = (((nblk << 7) + wn) >> 2) + (l & 15);
  const float bI = bih[jh]        + bhh[jh];
  const float bF = bih[512 + jh]  + bhh[512 + jh];
  const float bG = bih[1024 + jh] + bhh[1024 + jh];
  const float bO = bih[1536 + jh] + bhh[1536 + jh];
  const int crow = (by << 7) + wm + ((l>>4)<<2);
  const int kk = (back ? 512 : 0) + jh;            // col in x1 (0..1023)
  const size_t kpart = ((size_t)(kk >> 7) << 14) + ((size_t)((kk >> 5) & 3) << 12) + (kk & 31);
  const int colOff = back ? 896 : 384;
#pragma unroll
  for (int mi = 0; mi < 4; ++mi)
#pragma unroll
    for (int jr = 0; jr < 4; ++jr) {
      const int n = crow + mi*16 + jr;
      if (n < NN) {
        const float gi = acc[mi][0][jr] + bI;
        const float gf = acc[mi][1][jr] + bF;
        const float gg = acc[mi][2][jr] + bG;
        const float go = acc[mi][3][jr] + bO;
        const float c2 = sigm(gf) * c0[(size_t)n*512 + jh] + sigm(gi) * tanhf(gg);
        const float h  = sigm(go) * tanhf(c2);
        if (MODE == 0) {
          // A1X tiled with nkt=8 (x1 part only)
          const size_t off = (((size_t)(n >> 7) * 8) << 14) + kpart + ((size_t)(n & 127) << 5);
          ((unsigned char*)dst1)[off] = f2fp8(h);
        } else {
          ((bf16*)dst1)[(size_t)n*1408 + colOff + jh] = __float2bfloat16(h * 0.01f);
        }
      }
    }
}

// ---------------- split-K GEMM (bf16), counted-vmcnt pipeline (r8) ----------
__global__ __launch_bounds__(256) void gemm_bt_sk(const bf16* __restrict__ A,
                                                  const bf16* __restrict__ B,
                                                  float* __restrict__ Cp,
                                                  int Kp, int ldc, int ksteps)
{
  __shared__ alignas(16) char smem[32768];   // 2 x (A 8KB | B 8KB)
  const int t = threadIdx.x, w = t >> 6, l = t & 63;
  const int mbase = blockIdx.y << 7, nbase = blockIdx.x << 7;
  const int total = Kp >> 5;
  const int kstart = blockIdx.z * ksteps;
  int steps = total - kstart; if (steps > ksteps) steps = ksteps;
  const size_t ldb = (size_t)Kp * 2;
  const char* gA = (const char*)A + (size_t)(mbase + w*16 + (l>>2)) * ldb
                   + (size_t)((l&3)*16) + (size_t)kstart*64;
  const char* gB = (const char*)B + (size_t)(nbase + w*16 + (l>>2)) * ldb
                   + (size_t)((l&3)*16) + (size_t)kstart*64;
  const int wm = (w>>1)*64, wn = (w&1)*64;
  const int aoff = (wm + (l&15))*64 + (l>>4)*16;
  const int boff = 8192 + (wn + (l&15))*64 + (l>>4)*16;
  f32x4 acc[4][4] = {};
  const size_t chunk = ldb * 64;

  auto STAGE = [&](int buf, int kt) {
    char* lA = smem + buf*16384 + w*1024;
    char* lB = smem + buf*16384 + 8192 + w*1024;
    const size_t ko = (size_t)kt * 64;
    glds16(lA,        gA + ko);
    glds16(lA + 4096, gA + ko + chunk);
    glds16(lB,        gB + ko);
    glds16(lB + 4096, gB + ko + chunk);
  };

  STAGE(0, 0);
  if (steps > 1) STAGE(1, 1);
  int cur = 0;
  for (int kt = 0; kt < steps; ++kt) {
    if (kt + 1 < steps) asm volatile("s_waitcnt vmcnt(4)" ::: "memory");
    else                asm volatile("s_waitcnt vmcnt(0)" ::: "memory");
    __builtin_amdgcn_sched_barrier(0);
    __builtin_amdgcn_s_barrier();
    __builtin_amdgcn_sched_barrier(0);
    const char* base = smem + cur*16384;
    bf16x8 av[4], bv[4];
#pragma unroll
    for (int mi = 0; mi < 4; ++mi) av[mi] = *(const bf16x8*)(base + aoff + mi*1024);
#pragma unroll
    for (int ni = 0; ni < 4; ++ni) bv[ni] = *(const bf16x8*)(base + boff + ni*1024);
#pragma unroll
    for (int mi = 0; mi < 4; ++mi)
#pragma unroll
      for (int ni = 0; ni < 4; ++ni)
        acc[mi][ni] = __builtin_amdgcn_mfma_f32_16x16x32_bf16(av[mi], bv[ni], acc[mi][ni], 0, 0, 0);
    __builtin_amdgcn_sched_barrier(0);
    __builtin_amdgcn_s_barrier();
    __builtin_amdgcn_sched_barrier(0);
    if (kt + 2 < steps) STAGE(cur, kt + 2);
    cur ^= 1;
  }
  float* Cz = Cp + (size_t)blockIdx.z * ((size_t)(gridDim.y << 7) * ldc);
  const int crow = mbase + wm + ((l>>4)<<2);
  const int ccol = nbase + wn + (l&15);
#pragma unroll
  for (int mi = 0; mi < 4; ++mi)
#pragma unroll
    for (int ni = 0; ni < 4; ++ni) {
      float* cp = Cz + (size_t)(crow + mi*16)*ldc + (ccol + ni*16);
#pragma unroll
      for (int j = 0; j < 4; ++j) cp[(size_t)j*ldc] = acc[mi][ni][j];
    }
}

// ---------------- reduce kernels ----------------
__global__ void reduce_bf_pad(const float* __restrict__ p, bf16* __restrict__ dst, int Z)
{
  int k = blockIdx.x*256 + threadIdx.x;
  int r = blockIdx.y;
  if (k >= KADJ) return;
  const size_t psz = (size_t)gridDim.y * MP;
  float s = 0.f;
  if (k < NN)
    for (int z = 0; z < Z; ++z) s += p[(size_t)z*psz + (size_t)r*MP + k];
  dst[(size_t)r*KADJ + k] = __float2bfloat16(s);
}

__global__ void reduce_relu_bf(const float* __restrict__ p, const float* __restrict__ b,
                               bf16* __restrict__ dst)
{
  int idx = blockIdx.x*256 + threadIdx.x;   // MP*512
  int f = idx & 511;
  float s = b[f];
#pragma unroll
  for (int z = 0; z < 4; ++z) s += p[(size_t)z*MP*512 + idx];
  dst[idx] = __float2bfloat16(fmaxf(s, 0.f));
}

__global__ void reduce_bias_out(const float* __restrict__ p, const float* __restrict__ b,
                                float* __restrict__ out)
{
  int idx = blockIdx.x*256 + threadIdx.x;   // NN*256
  if (idx >= NN*256) return;
  int f = idx & 255;
  float s = b[f];
#pragma unroll
  for (int z = 0; z < 8; ++z) s += p[(size_t)z*MP*256 + idx];
  out[idx] = s;
}

// ---------------- fp8 tiled packing (merged) ----------------
// dst layout: [blk128][kt][kb:4][r:128][32B]; thread t covers row t>>1, 16 bytes
__global__ void pack_B8_all(const float* __restrict__ wih0f, const float* __restrict__ whh0f,
                            const float* __restrict__ wih0b, const float* __restrict__ whh0b,
                            const float* __restrict__ wih1f, const float* __restrict__ whh1f,
                            const float* __restrict__ wih1b, const float* __restrict__ whh1b,
                            unsigned char* __restrict__ B0f, unsigned char* __restrict__ B0b,
                            unsigned char* __restrict__ B1f, unsigned char* __restrict__ B1b)
{
  const int z = blockIdx.z;
  const float* wih; const float* whh; unsigned char* dst; int kx, nkt;
  if      (z == 0) { wih = wih0f; whh = whh0f; dst = B0f; kx = 588;  nkt = NKT0; }
  else if (z == 1) { wih = wih0b; whh = whh0b; dst = B0b; kx = 588;  nkt = NKT0; }
  else if (z == 2) { wih = wih1f; whh = whh1f; dst = B1f; kx = 1024; nkt = NKT1; }
  else             { wih = wih1b; whh = whh1b; dst = B1b; kx = 1024; nkt = NKT1; }
  if ((int)blockIdx.x >= nkt*4) return;
  const int kt = blockIdx.x >> 2, kbId = blockIdx.x & 3;
  const int t = threadIdx.x;
  const int r = t >> 1, kio = (t & 1) << 4;
  const int R = ((int)blockIdx.y << 7) + r;
  const int src = (((R >> 4) & 3) << 9) + ((R >> 6) << 4) + (R & 15);
  const int kbase = kt*128 + kbId*32 + kio;
  u8x16 v;
#pragma unroll
  for (int i = 0; i < 16; ++i) {
    const int k = kbase + i;
    float f = 0.f;
    if (k < kx) f = wih[(size_t)src*kx + k];
    else if (k < kx + 512) f = whh[(size_t)src*512 + (k - kx)];
    v[i] = f2fp8(f);
  }
  *(u8x16*)(dst + (((size_t)blockIdx.y*nkt + kt) << 14) + (kbId << 12) + (r << 5) + kio) = v;
}

// z 0/1: A0 dirs (x<36); z 2/3: A1 h0-tail dirs (x<16)
__global__ void pack_A8_all(const float* __restrict__ x, const float* __restrict__ h0,
                            unsigned char* __restrict__ a0f, unsigned char* __restrict__ a0b,
                            unsigned char* __restrict__ ahf, unsigned char* __restrict__ ahb)
{
  const int z = blockIdx.z;
  const int t = threadIdx.x;
  const int r = t >> 1, kio = (t & 1) << 4;
  const int n = ((int)blockIdx.y << 7) + r;
  if (z < 2) {
    const int kt = blockIdx.x >> 2, kbId = blockIdx.x & 3;
    const int kbase = kt*128 + kbId*32 + kio;
    const float* hsrc = h0 + (size_t)z * NH;
    u8x16 v;
#pragma unroll
    for (int i = 0; i < 16; ++i) {
      const int k = kbase + i;
      float f = 0.f;
      if (n < NN) {
        if (k < 588) f = x[(size_t)n*972 + k];
        else if (k < 1100) f = hsrc[(size_t)n*512 + (k - 588)];
      }
      v[i] = f2fp8(f);
    }
    unsigned char* dst = z ? a0b : a0f;
    *(u8x16*)(dst + (((size_t)blockIdx.y*NKT0 + kt) << 14) + (kbId << 12) + (r << 5) + kio) = v;
  } else {
    if ((int)blockIdx.x >= 16) return;
    const int ktl = blockIdx.x >> 2, kbId = blockIdx.x & 3;   // ktl 0..3
    const int kbase = ktl*128 + kbId*32 + kio;                // k-1024
    const float* hsrc = h0 + (size_t)(z) * NH;                // z=2 -> h0[2], z=3 -> h0[3]
    u8x16 v;
#pragma unroll
    for (int i = 0; i < 16; ++i) {
      const int k = kbase + i;
      float f = (n < NN) ? hsrc[(size_t)n*512 + k] : 0.f;
      v[i] = f2fp8(f);
    }
    unsigned char* dst = (z == 3) ? ahb : ahf;
    *(u8x16*)(dst + (((size_t)blockIdx.y*4 + ktl) << 14) + (kbId << 12) + (r << 5) + kio) = v;
  }
}

// ---------------- bf16 packing (GCN path, merged) ----------------
__global__ void pack_BT_all(const float* __restrict__ W1, bf16* __restrict__ BW1,
                            const float* __restrict__ W2, bf16* __restrict__ BW2)
{
  const int z = blockIdx.z;
  const float* W; bf16* dst; int Nc, K, nx, ny;
  if (z == 0) { W = W1; dst = BW1; Nc = 512; K = 1408; nx = 6; ny = 512; }
  else        { W = W2; dst = BW2; Nc = 256; K = 512;  nx = 2; ny = 256; }
  if ((int)blockIdx.x >= nx || (int)blockIdx.y >= ny) return;
  int k = blockIdx.x*256 + threadIdx.x;
  int n = blockIdx.y;
  if (k >= K) return;
  dst[(size_t)n*K + k] = __float2bfloat16(W[(size_t)k*Nc + n]);
}

__global__ void pack_prot(const float* __restrict__ x, bf16* __restrict__ afeat)
{
  int k = blockIdx.x*256 + threadIdx.x;    // [0,384)
  int n = blockIdx.y;
  if (k >= 384) return;
  float v = (n < NN) ? x[(size_t)n*972 + 588 + k] : 0.f;
  afeat[(size_t)n*1408 + k] = __float2bfloat16(v);
}

// ---------------- degree / norm ----------------
__global__ void deg_count(const int* __restrict__ ecols, int* __restrict__ deg)
{
  int e = blockIdx.x*256 + threadIdx.x;
  if (e < EE) atomicAdd(&deg[ecols[e]], 1);
}

__global__ void calc_dinv(const int* __restrict__ deg, float* __restrict__ dinv)
{
  int n = blockIdx.x*256 + threadIdx.x;
  if (n < NN) dinv[n] = 1.0f / sqrtf((float)(deg[n] + 1));
}

// ---------------- direct bf16 adjacency build (CAS pair-add) ----------------
// adjb row-major [c:MP][r:KADJ] bf16, pre-zeroed. KADJ even -> pair-aligned.
__global__ void adj_scatter_bf(const int* __restrict__ er, const int* __restrict__ ec,
                               const float* __restrict__ dinv,
                               unsigned int* __restrict__ adjw)
{
  int e = blockIdx.x*256 + threadIdx.x;
  int r, c; float v;
  if (e < EE)            { r = er[e]; c = ec[e]; v = dinv[r]*dinv[c]; }
  else if (e < EE + NN)  { r = c = e - EE; float d = dinv[r]; v = d*d; }
  else return;
  unsigned int* p = adjw + ((size_t)c*KADJ + r) / 2;
  const bool hi = (r & 1) != 0;
  unsigned int old = *p, assumed;
  do {
    assumed = old;
    unsigned short h = hi ? (unsigned short)(assumed >> 16)
                          : (unsigned short)(assumed & 0xffffu);
    unsigned short nh = f2bf_bits(bf_bits2f(h) + v);
    unsigned int nw = hi ? ((assumed & 0x0000ffffu) | ((unsigned int)nh << 16))
                         : ((assumed & 0xffff0000u) | (unsigned int)nh);
    if (nw == assumed) break;
    old = atomicCAS(p, assumed, nw);
  } while (old != assumed);
}

// ---------------- workspace layout (bytes), total <= 93,339,648 (proven) ----
#define OFF_DEG   ((size_t)0)
#define OFF_DINV  ((size_t)16384)
#define OFF_BW2   ((size_t)32768)
#define OFF_B0F   ((size_t)294912)     // fp8: 2,359,296
#define OFF_B0B   ((size_t)4882432)
#define OFF_B1F   ((size_t)9469952)    // fp8: 3,145,728
#define OFF_B1B   ((size_t)15761408)
#define OFF_BW1   ((size_t)22052864)
#define OFF_A0F   ((size_t)23494656)   // fp8: 4,276,224
#define OFF_A0B   ((size_t)31809536)
#define OFF_A1X   ((size_t)40124416)   // shared x1, nkt=8: 3,801,088
#define OFF_A1HF  ((size_t)43925504)   // h0 tail fwd, 4kt: 1,900,544
#define OFF_A1HB  ((size_t)45826048)   // -> 47,726,592
#define OFF_G     ((size_t)62930944)
// ---- overlays (temporal reuse) ----
#define OFF_AFEAT OFF_A0F              // alive: pack_prot .. xwt1 gemm
#define OFF_XW1P  OFF_G                // xwt1 partials 30,408,704
#define OFF_XWT1B OFF_B0F              // 3,702,784 (B0 dead after L0)
#define OFF_ADJB  ((size_t)4194304)    // 26,845,184 (B0b/B1/BW1/Afeat dead after xwt1)
#define OFF_H1P   ((size_t)40124416)   // agg1 partials 30,408,704
#define OFF_H1    ((size_t)70533120)
#define OFF_XW2P  ((size_t)74334208)
#define OFF_XWT2B ((size_t)89538560)
#define OFF_O2P   ((size_t)40124416)   // agg2 partials (h1p dead)

extern "C" void kernel_launch(void* const* d_in, const int* in_sizes, int n_in,
                              void* d_out, int out_size, void* d_ws, size_t ws_size,
                              hipStream_t stream)
{
  const float* x    = (const float*)d_in[0];
  const int*   ei   = (const int*)d_in[1];
  const float* h0   = (const float*)d_in[2];
  const float* c0   = (const float*)d_in[3];
  const float* wih0f = (const float*)d_in[4];
  const float* whh0f = (const float*)d_in[5];
  const float* bih0f = (const float*)d_in[6];
  const float* bhh0f = (const float*)d_in[7];
  const float* wih0b = (const float*)d_in[8];
  const float* whh0b = (const float*)d_in[9];
  const float* bih0b = (const float*)d_in[10];
  const float* bhh0b = (const float*)d_in[11];
  const float* wih1f = (const float*)d_in[12];
  const float* whh1f = (const float*)d_in[13];
  const float* bih1f = (const float*)d_in[14];
  const float* bhh1f = (const float*)d_in[15];
  const float* wih1b = (const float*)d_in[16];
  const float* whh1b = (const float*)d_in[17];
  const float* bih1b = (const float*)d_in[18];
  const float* bhh1b = (const float*)d_in[19];
  const float* W1 = (const float*)d_in[20];
  const float* b1 = (const float*)d_in[21];
  const float* W2 = (const float*)d_in[22];
  const float* b2 = (const float*)d_in[23];

  char* ws = (char*)d_ws;
  int*   deg  = (int*)(ws + OFF_DEG);
  float* dinv = (float*)(ws + OFF_DINV);
  unsigned char* B0f8 = (unsigned char*)(ws + OFF_B0F);
  unsigned char* B0b8 = (unsigned char*)(ws + OFF_B0B);
  unsigned char* B1f8 = (unsigned char*)(ws + OFF_B1F);
  unsigned char* B1b8 = (unsigned char*)(ws + OFF_B1B);
  bf16* BW1 = (bf16*)(ws + OFF_BW1);
  bf16* BW2 = (bf16*)(ws + OFF_BW2);
  unsigned char* A0f8 = (unsigned char*)(ws + OFF_A0F);
  unsigned char* A0b8 = (unsigned char*)(ws + OFF_A0B);
  unsigned char* A1X8 = (unsigned char*)(ws + OFF_A1X);
  unsigned char* A1HF = (unsigned char*)(ws + OFF_A1HF);
  unsigned char* A1HB = (unsigned char*)(ws + OFF_A1HB);
  bf16* Afeat = (bf16*)(ws + OFF_AFEAT);
  float* xw1p  = (float*)(ws + OFF_XW1P);
  bf16*  xwt1b = (bf16*)(ws + OFF_XWT1B);
  bf16*  adjb  = (bf16*)(ws + OFF_ADJB);
  float* h1p   = (float*)(ws + OFF_H1P);
  bf16*  h1bf  = (bf16*)(ws + OFF_H1);
  float* xw2p  = (float*)(ws + OFF_XW2P);
  bf16*  xwt2b = (bf16*)(ws + OFF_XWT2B);
  float* o2p   = (float*)(ws + OFF_O2P);
  float* outp = (float*)d_out;

  // degree + norm
  hipMemsetAsync(deg, 0, (size_t)NN*4, stream);
  deg_count<<<dim3((EE+255)/256), 256, 0, stream>>>(ei + EE, deg);
  calc_dinv<<<dim3(15), 256, 0, stream>>>(deg, dinv);

  // weight packing: fp8 tiled (LSTM, merged), bf16 (GCN, merged)
  pack_B8_all<<<dim3(NKT1*4, 16, 4), 256, 0, stream>>>(
      wih0f, whh0f, wih0b, whh0b, wih1f, whh1f, wih1b, whh1b,
      B0f8, B0b8, B1f8, B1b8);
  pack_BT_all<<<dim3(6, 512, 2), 256, 0, stream>>>(W1, BW1, W2, BW2);

  // activations packing (fp8 tiled, merged)
  pack_A8_all<<<dim3(NKT0*4, 29, 4), 256, 0, stream>>>(x, h0, A0f8, A0b8, A1HF, A1HB);

  // LSTM layer 0: MX-fp8, merged f+b, gate fused; writes x1 fp8 into shared A1X
  gemm_lstm8<0><<<dim3(32, 29), 256, 0, stream>>>(
      A0f8, A0f8, B0f8, c0,              bih0f, bhh0f,
      A0b8, A0b8, B0b8, c0 + (size_t)NH, bih0b, bhh0b,
      A1X8, NKT0, NKT0, 16);

  // feat: prot part (A0 dead; Afeat overlays it)
  pack_prot<<<dim3(2, MP), 256, 0, stream>>>(x, Afeat);

  // LSTM layer 1: MX-fp8, shared-x1 A + per-dir h0 tail; writes x_p/100 into feat
  gemm_lstm8<1><<<dim3(32, 29), 256, 0, stream>>>(
      A1X8, A1HF, B1f8, c0 + (size_t)2*NH, bih1f, bhh1f,
      A1X8, A1HB, B1b8, c0 + (size_t)3*NH, bih1b, bhh1b,
      Afeat, 8, NKT1, 16);

  // XW1^T = W1^T @ feat^T  split-K=4 (bf16)
  gemm_bt_sk<<<dim3(29, 4, 4), 256, 0, stream>>>(BW1, Afeat, xw1p, 1408, MP, 11);
  reduce_bf_pad<<<dim3(15, 512), 256, 0, stream>>>(xw1p, xwt1b, 4);

  // dense normalized adjacency, built DIRECTLY in bf16 (B0b..Afeat dead)
  hipMemsetAsync(adjb, 0, (size_t)MP*KADJ*2, stream);
  adj_scatter_bf<<<dim3((EE+NN+255)/256), 256, 0, stream>>>(
      ei, ei + EE, dinv, (unsigned int*)adjb);

  // out1 = relu(Adj @ XW1 + b1) -> bf16, split-K=4 (113 steps -> 29,29,29,26)
  gemm_bt_sk<<<dim3(4, 29, 4), 256, 0, stream>>>(adjb, xwt1b, h1p, KADJ, 512, 29);
  reduce_relu_bf<<<dim3(MP*512/256), 256, 0, stream>>>(h1p, b1, h1bf);

  // XW2^T = W2^T @ h1^T  split-K=4
  gemm_bt_sk<<<dim3(29, 2, 4), 256, 0, stream>>>(BW2, h1bf, xw2p, 512, MP, 4);
  reduce_bf_pad<<<dim3(15, 256), 256, 0, stream>>>(xw2p, xwt2b, 4);

  // out = Adj @ XW2 + b2, split-K=8
  gemm_bt_sk<<<dim3(2, 29, 8), 256, 0, stream>>>(adjb, xwt2b, o2p, KADJ, 256, 15);
  reduce_bias_out<<<dim3(3600), 256, 0, stream>>>(o2p, b2, outp);
}